// Round 4
// baseline (147.760 us; speedup 1.0000x reference)
//
#include <hip/hip_runtime.h>

#define BATCH 4
#define NPTS 16384
#define MPTS 16384
#define NH 32
#define NK 15
#define NF 64
#define NC 64

typedef short short8 __attribute__((ext_vector_type(8)));
typedef float floatx4 __attribute__((ext_vector_type(4)));

__device__ __forceinline__ unsigned short f2bf(float x) {
    unsigned int u = __builtin_bit_cast(unsigned int, x);
    u = u + 0x7FFFu + ((u >> 16) & 1u);   // RNE
    return (unsigned short)(u >> 16);
}

// pack two floats -> bf16x2 dword by truncation (1 v_perm)
__device__ __forceinline__ unsigned pack_trunc(float lo, float hi) {
    return __builtin_amdgcn_perm(__builtin_bit_cast(unsigned, hi),
                                 __builtin_bit_cast(unsigned, lo), 0x07060302u);
}

// ---------- fused prep: blocks [0,32) = V re-layout; [32, 2080) = feat fp32->bf16 ----------
__global__ void prep_kernel(const float* __restrict__ kv, const float* __restrict__ feat,
                            unsigned short* __restrict__ vp, unsigned short* __restrict__ featbf) {
    if (blockIdx.x < 32) {
        // kappa = f*16 + k (k padded to 16, zero for k==15). KF = 1024 -> 32 mfma steps.
        const int gid = blockIdx.x * 256 + threadIdx.x;        // 8192 threads
        const int lane = gid & 63;
        const int ct   = (gid >> 6) & 3;
        const int kk   = gid >> 8;                             // 0..31
        const int c    = ct * 16 + (lane & 15);
        const int kap0 = kk * 32 + (lane >> 4) * 8;
        unsigned int o[4];
        #pragma unroll
        for (int jj = 0; jj < 4; jj++) {
            unsigned short lo, hi;
            {
                const int kap = kap0 + jj * 2;
                const int f = kap >> 4, k = kap & 15;
                lo = (k < NK) ? f2bf(kv[((size_t)(k * NF + f)) * NC + c]) : (unsigned short)0;
            }
            {
                const int kap = kap0 + jj * 2 + 1;
                const int f = kap >> 4, k = kap & 15;
                hi = (k < NK) ? f2bf(kv[((size_t)(k * NF + f)) * NC + c]) : (unsigned short)0;
            }
            o[jj] = (unsigned)lo | ((unsigned)hi << 16);
        }
        *(uint4*)(vp + (size_t)gid * 8) = make_uint4(o[0], o[1], o[2], o[3]);
    } else {
        const int gid = (blockIdx.x - 32) * 256 + threadIdx.x; // 524288 threads x 8 elems
        const size_t base = (size_t)gid * 8;
        float4 a = *(const float4*)(feat + base);
        float4 b = *(const float4*)(feat + base + 4);
        uint4 o;
        o.x = (unsigned)f2bf(a.x) | ((unsigned)f2bf(a.y) << 16);
        o.y = (unsigned)f2bf(a.z) | ((unsigned)f2bf(a.w) << 16);
        o.z = (unsigned)f2bf(b.x) | ((unsigned)f2bf(b.y) << 16);
        o.w = (unsigned)f2bf(b.z) | ((unsigned)f2bf(b.w) << 16);
        *(uint4*)(featbf + base) = o;
    }
}

// ---------- main kernel: R4 = m-tile 32, 512 threads / 8 waves ----------
// Rationale (R0-R3 falsified occupancy levers): each 16-pt block re-read full V
// (128 KB L2) and paid 8 barriers + prologue latency. m=32 halves per-point
// fixed costs and halves V L2 traffic (512->256 MB) by reusing each vp load
// for BOTH row-tiles (2 MFMAs per uB).
// Wave roles: g=tid>>6 in [0,8): col-tile ct=g&3, kappa-half kh=g>>2.
// Each wave computes 2 row-tiles x 1 col-tile over its 8 kk-steps per f-half;
// cross-wave (kh) partials reduced via ob[2][32][68] in LDS.
__global__ __launch_bounds__(512, 6) void kpconv_kernel(
    const float* __restrict__ points,          // [B,N,3]
    const unsigned short* __restrict__ featbf, // [B,N,F] bf16 (ws)
    const float* __restrict__ outpts,          // [B,M,3]
    const float* __restrict__ kpts,            // [K,3]
    const unsigned short* __restrict__ vp,     // einsum2 B-frag-ordered V bf16 (ws)
    const int*   __restrict__ nbr,             // [B,M,H]
    float* __restrict__ out)                   // [B,M,C]
{
    // awf: wf in einsum2 A-frag order for ONE kappa-half, 32 pts:
    //   [kk 0..15][chunk 0..127][8 shorts], chunk = (p4^kk) | q2<<4 | (p>>4)<<6.
    // Prologue aliases it as skewed rel4 (1151 float4 = 18416 B);
    // epilogue as ob[2][32][68] float (17408 B).
    __shared__ __align__(16) unsigned short awf[16 * 1024];   // 32768 B
    // feat_s per wave: [floc 0..31][h 0..31 bf16] row stride 36 shorts (+pad)
    __shared__ __align__(16) unsigned short feat_s[8 * 1160]; // 18560 B
    __shared__ __align__(8) unsigned short idx_s[1024];       //  2048 B (idx < 16384 fits u16)
    __shared__ float opt_s[96];
    __shared__ float kp_s[48];
    // total 53952 B -> 3 blocks/CU (24 waves)

    const int tid   = threadIdx.x;
    // XCD-aware partition: round-robin dispatch sends blockIdx ≡ x (mod 8) to XCD x,
    // so batch = blockIdx & 3 pins each XCD's L2 to a single batch's 2 MB feature slice.
    const int batch = blockIdx.x & 3;
    const int m0    = (blockIdx.x >> 2) << 5;

    if (tid < 48) kp_s[tid] = (tid < 45) ? kpts[tid] : 1e9f;   // sentinel -> w=0 for k=15
    if (tid >= 64 && tid < 160)
        opt_s[tid - 64] = outpts[(size_t)(batch * MPTS + m0) * 3 + (tid - 64)];
    {
        // packed: each thread loads int2 (8B coalesced), writes one b32 of two u16 idx
        const size_t nb = (size_t)(batch * MPTS + m0) * NH;
        const int2 nn = *(const int2*)(nbr + nb + tid * 2);
        *(unsigned*)&idx_s[tid * 2] =
            (unsigned)(unsigned short)nn.x | ((unsigned)(unsigned short)nn.y << 16);
    }
    __syncthreads();   // B1: idx/opt/kp ready

    const int g    = tid >> 6;    // wave id 0..7; feat_s partition g is wave-private
    const int lane = tid & 63;
    const int cl   = lane & 15;
    const int q    = lane >> 4;
    const int sa   = cl;          // h-pair handled by this lane in staging
    const int sfc  = q;           // f-chunk of 8 shorts in staging

    const unsigned short* fbase = featbf + (size_t)(batch * NPTS) * NF;

    // ---- issue iter-0 AND iter-1 gathers immediately (depth-2 pipeline head) ----
    uint4 praA, prbA, praB, prbB;
    {
        const int srow0 = (0 * 8 + g) * 32 + sa * 2;           // it=0: r=0, fh=0
        const int ida0 = idx_s[srow0], idb0 = idx_s[srow0 + 1];
        praA = *(const uint4*)(fbase + (size_t)ida0 * NF + sfc * 8);
        prbA = *(const uint4*)(fbase + (size_t)idb0 * NF + sfc * 8);
        const int srow1 = (1 * 8 + g) * 32 + sa * 2;           // it=1: r=1, fh=0
        const int ida1 = idx_s[srow1], idb1 = idx_s[srow1 + 1];
        praB = *(const uint4*)(fbase + (size_t)ida1 * NF + sfc * 8);
        prbB = *(const uint4*)(fbase + (size_t)idb1 * NF + sfc * 8);
    }

    // ---- stage rel coords into awf alias (skewed: row -> row + (row>>3)) ----
    float4* rel4 = (float4*)awf;
    #pragma unroll
    for (int rr = 0; rr < 2; rr++) {
        const int row = tid * 2 + rr;            // 0..1023 = p*32 + h
        const int id  = idx_s[row];
        const int pm  = row >> 5;
        const float* pp = points + ((size_t)(batch * NPTS) + id) * 3;
        rel4[row + (row >> 3)] = make_float4(pp[0] - opt_s[pm * 3 + 0],
                                             pp[1] - opt_s[pm * 3 + 1],
                                             pp[2] - opt_s[pm * 3 + 2], 0.f);
    }
    __syncthreads();   // B2: rel ready

    // ---- compute all w A-frags for this wave's 4 points (held in registers) ----
    short8 af[4];
    {
        const float kx = kp_s[cl * 3 + 0];
        const float ky = kp_s[cl * 3 + 1];
        const float kz = kp_s[cl * 3 + 2];
        #pragma unroll
        for (int rp = 0; rp < 4; rp++) {
            const int p = rp * 8 + g;
            float wv[8];
            #pragma unroll
            for (int j = 0; j < 8; j++) {
                // row = p*32 + q*8 + j  ->  skewed index 36p + 9q + j
                const float4 rr = rel4[36 * p + 9 * q + j];    // broadcast across cl
                const float dx = rr.x - kx, dy = rr.y - ky, dz = rr.z - kz;
                const float d2 = dx * dx + dy * dy + dz * dz;
                wv[j] = fmaxf(1.f - __builtin_amdgcn_sqrtf(d2), 0.f);  // EXTENT=1
            }
            uint4 ua;
            ua.x = pack_trunc(wv[0], wv[1]);
            ua.y = pack_trunc(wv[2], wv[3]);
            ua.z = pack_trunc(wv[4], wv[5]);
            ua.w = pack_trunc(wv[6], wv[7]);
            af[rp] = __builtin_bit_cast(short8, ua);
        }
    }
    __syncthreads();   // B3: rel4 dead -> awf free for einsum1 output

    floatx4 a00 = {0.f, 0.f, 0.f, 0.f};   // row-tile 0, even kk
    floatx4 a01 = {0.f, 0.f, 0.f, 0.f};   // row-tile 0, odd kk
    floatx4 a10 = {0.f, 0.f, 0.f, 0.f};   // row-tile 1, even kk
    floatx4 a11 = {0.f, 0.f, 0.f, 0.f};   // row-tile 1, odd kk
    const int ct  = g & 3;                // col-tile of 16 C
    const int kh8 = (g >> 2) * 8;         // this wave's kk-range base within each half
    const unsigned short* vpg = vp + ct * 512 + lane * 8;
    unsigned short* dp = &feat_s[g * 1160 + sfc * 288 + sa * 2];   // sfc*8 rows of 36

    #pragma unroll
    for (int it = 0; it < 8; it++) {
        const int r  = it & 3;      // round (8 points each)
        const int p  = r * 8 + g;
        const int p4 = p & 15;
        const int pu = p >> 4;      // row-tile bit (wave-uniform)

        // (a) stage this iter's f-half from prefetched regs (wave-private LDS, no barrier)
        *(unsigned*)(dp + 0 * 36) = __builtin_amdgcn_perm(prbA.x, praA.x, 0x05040100u);
        *(unsigned*)(dp + 1 * 36) = __builtin_amdgcn_perm(prbA.x, praA.x, 0x07060302u);
        *(unsigned*)(dp + 2 * 36) = __builtin_amdgcn_perm(prbA.y, praA.y, 0x05040100u);
        *(unsigned*)(dp + 3 * 36) = __builtin_amdgcn_perm(prbA.y, praA.y, 0x07060302u);
        *(unsigned*)(dp + 4 * 36) = __builtin_amdgcn_perm(prbA.z, praA.z, 0x05040100u);
        *(unsigned*)(dp + 5 * 36) = __builtin_amdgcn_perm(prbA.z, praA.z, 0x07060302u);
        *(unsigned*)(dp + 6 * 36) = __builtin_amdgcn_perm(prbA.w, praA.w, 0x05040100u);
        *(unsigned*)(dp + 7 * 36) = __builtin_amdgcn_perm(prbA.w, praA.w, 0x07060302u);

        // (b) rotate pipeline and prefetch it+2 (fully unrolled -> rotation is free)
        praA = praB; prbA = prbB;
        if (it < 6) {
            const int nit = it + 2;
            const int nfh = nit >> 2, nr = nit & 3;
            const int srow = (nr * 8 + g) * 32 + sa * 2;
            const int id0 = idx_s[srow], id1 = idx_s[srow + 1];
            praB = *(const uint4*)(fbase + (size_t)id0 * NF + nfh * 32 + sfc * 8);
            prbB = *(const uint4*)(fbase + (size_t)id1 * NF + nfh * 32 + sfc * 8);
        }

        // (c) einsum1: 2 f-tiles of 16 for point p
        #pragma unroll
        for (int t = 0; t < 2; t++) {
            const uint4 ub = *(const uint4*)&feat_s[g * 1160 + (t * 16 + cl) * 36 + q * 8];
            floatx4 dd = {0.f, 0.f, 0.f, 0.f};
            dd = __builtin_amdgcn_mfma_f32_16x16x32_bf16(af[r], __builtin_bit_cast(short8, ub), dd, 0, 0, 0);
            const int kk    = 8 * t + (cl >> 1);               // local kappa-chunk 0..15
            const int q2    = (2 * cl + (q >> 1)) & 3;
            const int chunk = (p4 ^ kk) | (q2 << 4) | (pu << 6);
            unsigned* wp = (unsigned*)awf + kk * 512 + chunk * 4 + (q & 1) * 2;
            wp[0] = pack_trunc(dd[0], dd[1]);
            wp[1] = pack_trunc(dd[2], dd[3]);
        }

        // (d) at f-half boundary: einsum2 partial over this kappa-half
        if (it == 3) {
            __syncthreads();   // B4: awf (fh=0) complete
            __builtin_amdgcn_s_setprio(1);
            #pragma unroll 4
            for (int kkl = 0; kkl < 8; kkl++) {
                const int kka = kh8 + kkl;                       // kk within half, 0..15
                const uint4 uB = *(const uint4*)(vpg + (size_t)kka * 2048);
                const int ch = (cl ^ kka) | (q << 4);
                const uint4 uA0 = *(const uint4*)&awf[kka * 1024 + ch * 8];
                const uint4 uA1 = *(const uint4*)&awf[kka * 1024 + (ch | 64) * 8];
                if (kkl & 1) {
                    a01 = __builtin_amdgcn_mfma_f32_16x16x32_bf16(
                        __builtin_bit_cast(short8, uA0), __builtin_bit_cast(short8, uB), a01, 0, 0, 0);
                    a11 = __builtin_amdgcn_mfma_f32_16x16x32_bf16(
                        __builtin_bit_cast(short8, uA1), __builtin_bit_cast(short8, uB), a11, 0, 0, 0);
                } else {
                    a00 = __builtin_amdgcn_mfma_f32_16x16x32_bf16(
                        __builtin_bit_cast(short8, uA0), __builtin_bit_cast(short8, uB), a00, 0, 0, 0);
                    a10 = __builtin_amdgcn_mfma_f32_16x16x32_bf16(
                        __builtin_bit_cast(short8, uA1), __builtin_bit_cast(short8, uB), a10, 0, 0, 0);
                }
            }
            __builtin_amdgcn_s_setprio(0);
            __syncthreads();   // B5: einsum2 reads done -> awf reusable for fh=1
        }
    }

    // ---- einsum2 second kappa-half ----
    __syncthreads();   // B6: awf (fh=1) complete
    __builtin_amdgcn_s_setprio(1);
    #pragma unroll 4
    for (int kkl = 0; kkl < 8; kkl++) {
        const int kka = kh8 + kkl;
        const uint4 uB = *(const uint4*)(vpg + (size_t)(16 + kka) * 2048);
        const int ch = (cl ^ kka) | (q << 4);
        const uint4 uA0 = *(const uint4*)&awf[kka * 1024 + ch * 8];
        const uint4 uA1 = *(const uint4*)&awf[kka * 1024 + (ch | 64) * 8];
        if (kkl & 1) {
            a01 = __builtin_amdgcn_mfma_f32_16x16x32_bf16(
                __builtin_bit_cast(short8, uA0), __builtin_bit_cast(short8, uB), a01, 0, 0, 0);
            a11 = __builtin_amdgcn_mfma_f32_16x16x32_bf16(
                __builtin_bit_cast(short8, uA1), __builtin_bit_cast(short8, uB), a11, 0, 0, 0);
        } else {
            a00 = __builtin_amdgcn_mfma_f32_16x16x32_bf16(
                __builtin_bit_cast(short8, uA0), __builtin_bit_cast(short8, uB), a00, 0, 0, 0);
            a10 = __builtin_amdgcn_mfma_f32_16x16x32_bf16(
                __builtin_bit_cast(short8, uA1), __builtin_bit_cast(short8, uB), a10, 0, 0, 0);
        }
    }
    __builtin_amdgcn_s_setprio(0);

    // ---- epilogue: cross-wave (kh) reduction via ob[2][32][68], coalesced store ----
    __syncthreads();   // B7: all einsum2 reads of awf done
    float* ob = (float*)awf;                    // [kh][row 0..31][68] = 17408 B
    const int kh = g >> 2;
    #pragma unroll
    for (int ri = 0; ri < 4; ri++) {
        ob[(kh * 32 +      q * 4 + ri) * 68 + ct * 16 + cl] = a00[ri] + a01[ri];
        ob[(kh * 32 + 16 + q * 4 + ri) * 68 + ct * 16 + cl] = a10[ri] + a11[ri];
    }
    __syncthreads();   // B8: staged
    {
        const int row = tid >> 4;               // 0..31
        const int c4  = tid & 15;               // float4 slot
        const floatx4 v0 = *(const floatx4*)&ob[row * 68 + c4 * 4];
        const floatx4 v1 = *(const floatx4*)&ob[(32 + row) * 68 + c4 * 4];
        const floatx4 v = v0 + v1;
        floatx4* dst = (floatx4*)&out[((size_t)(batch * MPTS + m0 + row)) * NC + c4 * 4];
        __builtin_nontemporal_store(v, dst);    // out never re-read: bypass L2
    }
}

extern "C" void kernel_launch(void* const* d_in, const int* in_sizes, int n_in,
                              void* d_out, int out_size, void* d_ws, size_t ws_size,
                              hipStream_t stream) {
    const float* points   = (const float*)d_in[0];
    const float* features = (const float*)d_in[1];
    const float* outpts   = (const float*)d_in[2];
    const float* kpts     = (const float*)d_in[3];
    const float* kvals    = (const float*)d_in[4];
    const int*   nbr      = (const int*)d_in[5];
    float* out = (float*)d_out;

    unsigned short* vp     = (unsigned short*)d_ws;                   // 131072 B
    unsigned short* featbf = (unsigned short*)((char*)d_ws + 131072); // 8 MB

    prep_kernel<<<2080, 256, 0, stream>>>(kvals, features, vp, featbf);

    const int blocks = BATCH * (MPTS / 32);   // 2048
    kpconv_kernel<<<blocks, 512, 0, stream>>>(points, featbf, outpts, kpts, vp, nbr, out);
}

// Round 5
// 138.665 us; speedup vs baseline: 1.0656x; 1.0656x over previous
//
#include <hip/hip_runtime.h>

#define BATCH 4
#define NPTS 16384
#define MPTS 16384
#define NH 32
#define NK 15
#define NF 64
#define NC 64

typedef short short8 __attribute__((ext_vector_type(8)));
typedef float floatx4 __attribute__((ext_vector_type(4)));

__device__ __forceinline__ unsigned short f2bf(float x) {
    unsigned int u = __builtin_bit_cast(unsigned int, x);
    u = u + 0x7FFFu + ((u >> 16) & 1u);   // RNE
    return (unsigned short)(u >> 16);
}

// pack two floats -> bf16x2 dword by truncation (1 v_perm)
__device__ __forceinline__ unsigned pack_trunc(float lo, float hi) {
    return __builtin_amdgcn_perm(__builtin_bit_cast(unsigned, hi),
                                 __builtin_bit_cast(unsigned, lo), 0x07060302u);
}

// ---------- fused prep: blocks [0,32) = V re-layout; [32, 2080) = feat fp32->bf16 ----------
__global__ void prep_kernel(const float* __restrict__ kv, const float* __restrict__ feat,
                            unsigned short* __restrict__ vp, unsigned short* __restrict__ featbf) {
    if (blockIdx.x < 32) {
        // kappa = f*16 + k (k padded to 16, zero for k==15). KF = 1024 -> 32 mfma steps.
        const int gid = blockIdx.x * 256 + threadIdx.x;        // 8192 threads
        const int lane = gid & 63;
        const int ct   = (gid >> 6) & 3;
        const int kk   = gid >> 8;                             // 0..31
        const int c    = ct * 16 + (lane & 15);
        const int kap0 = kk * 32 + (lane >> 4) * 8;
        unsigned int o[4];
        #pragma unroll
        for (int jj = 0; jj < 4; jj++) {
            unsigned short lo, hi;
            {
                const int kap = kap0 + jj * 2;
                const int f = kap >> 4, k = kap & 15;
                lo = (k < NK) ? f2bf(kv[((size_t)(k * NF + f)) * NC + c]) : (unsigned short)0;
            }
            {
                const int kap = kap0 + jj * 2 + 1;
                const int f = kap >> 4, k = kap & 15;
                hi = (k < NK) ? f2bf(kv[((size_t)(k * NF + f)) * NC + c]) : (unsigned short)0;
            }
            o[jj] = (unsigned)lo | ((unsigned)hi << 16);
        }
        *(uint4*)(vp + (size_t)gid * 8) = make_uint4(o[0], o[1], o[2], o[3]);
    } else {
        const int gid = (blockIdx.x - 32) * 256 + threadIdx.x; // 524288 threads x 8 elems
        const size_t base = (size_t)gid * 8;
        float4 a = *(const float4*)(feat + base);
        float4 b = *(const float4*)(feat + base + 4);
        uint4 o;
        o.x = (unsigned)f2bf(a.x) | ((unsigned)f2bf(a.y) << 16);
        o.y = (unsigned)f2bf(a.z) | ((unsigned)f2bf(a.w) << 16);
        o.z = (unsigned)f2bf(b.x) | ((unsigned)f2bf(b.y) << 16);
        o.w = (unsigned)f2bf(b.z) | ((unsigned)f2bf(b.w) << 16);
        *(uint4*)(featbf + base) = o;
    }
}

// ---------- main kernel: R5 = R4 structure (m-tile 32, 512 thr / 8 waves), bounds (512,4) ----------
// R4 post-mortem: __launch_bounds__(512,6) capped regalloc at ~84 VGPRs; demand
// (~90: 4 acc + 4 prefetch uint4 + af[4] + addressing) exceeded it -> scratch
// spill (VGPR_Count 40, WRITE +37 MB, FETCH +7 MB). Third spill occurrence;
// lesson: the 2nd launch_bounds arg only throttles the ALLOCATOR here, because
// residency is LDS-limited anyway (163840/54272 = 3 blocks/CU = 6 waves/SIMD).
// (512,4) -> 128-VGPR cap: demand fits, residency unchanged.
__global__ __launch_bounds__(512, 4) void kpconv_kernel(
    const float* __restrict__ points,          // [B,N,3]
    const unsigned short* __restrict__ featbf, // [B,N,F] bf16 (ws)
    const float* __restrict__ outpts,          // [B,M,3]
    const float* __restrict__ kpts,            // [K,3]
    const unsigned short* __restrict__ vp,     // einsum2 B-frag-ordered V bf16 (ws)
    const int*   __restrict__ nbr,             // [B,M,H]
    float* __restrict__ out)                   // [B,M,C]
{
    // awf: wf in einsum2 A-frag order for ONE kappa-half, 32 pts:
    //   [kk 0..15][chunk 0..127][8 shorts], chunk = (p4^kk) | q2<<4 | (p>>4)<<6.
    // Prologue aliases it as skewed rel4 (1151 float4 = 18416 B);
    // epilogue as ob[2][32][68] float (17408 B).
    __shared__ __align__(16) unsigned short awf[16 * 1024];   // 32768 B
    // feat_s per wave: [floc 0..31][h 0..31 bf16] row stride 36 shorts (+pad)
    __shared__ __align__(16) unsigned short feat_s[8 * 1160]; // 18560 B
    __shared__ __align__(8) unsigned short idx_s[1024];       //  2048 B (idx < 16384 fits u16)
    __shared__ float opt_s[96];
    __shared__ float kp_s[48];
    // total 53952 B -> 3 blocks/CU (24 waves)

    const int tid   = threadIdx.x;
    // XCD-aware partition: round-robin dispatch sends blockIdx ≡ x (mod 8) to XCD x,
    // so batch = blockIdx & 3 pins each XCD's L2 to a single batch's 2 MB feature slice.
    const int batch = blockIdx.x & 3;
    const int m0    = (blockIdx.x >> 2) << 5;

    if (tid < 48) kp_s[tid] = (tid < 45) ? kpts[tid] : 1e9f;   // sentinel -> w=0 for k=15
    if (tid >= 64 && tid < 160)
        opt_s[tid - 64] = outpts[(size_t)(batch * MPTS + m0) * 3 + (tid - 64)];
    {
        // packed: each thread loads int2 (8B coalesced), writes one b32 of two u16 idx
        const size_t nb = (size_t)(batch * MPTS + m0) * NH;
        const int2 nn = *(const int2*)(nbr + nb + tid * 2);
        *(unsigned*)&idx_s[tid * 2] =
            (unsigned)(unsigned short)nn.x | ((unsigned)(unsigned short)nn.y << 16);
    }
    __syncthreads();   // B1: idx/opt/kp ready

    const int g    = tid >> 6;    // wave id 0..7; feat_s partition g is wave-private
    const int lane = tid & 63;
    const int cl   = lane & 15;
    const int q    = lane >> 4;
    const int sa   = cl;          // h-pair handled by this lane in staging
    const int sfc  = q;           // f-chunk of 8 shorts in staging

    const unsigned short* fbase = featbf + (size_t)(batch * NPTS) * NF;

    // ---- issue iter-0 AND iter-1 gathers immediately (depth-2 pipeline head) ----
    uint4 praA, prbA, praB, prbB;
    {
        const int srow0 = (0 * 8 + g) * 32 + sa * 2;           // it=0: r=0, fh=0
        const int ida0 = idx_s[srow0], idb0 = idx_s[srow0 + 1];
        praA = *(const uint4*)(fbase + (size_t)ida0 * NF + sfc * 8);
        prbA = *(const uint4*)(fbase + (size_t)idb0 * NF + sfc * 8);
        const int srow1 = (1 * 8 + g) * 32 + sa * 2;           // it=1: r=1, fh=0
        const int ida1 = idx_s[srow1], idb1 = idx_s[srow1 + 1];
        praB = *(const uint4*)(fbase + (size_t)ida1 * NF + sfc * 8);
        prbB = *(const uint4*)(fbase + (size_t)idb1 * NF + sfc * 8);
    }

    // ---- stage rel coords into awf alias (skewed: row -> row + (row>>3)) ----
    float4* rel4 = (float4*)awf;
    #pragma unroll
    for (int rr = 0; rr < 2; rr++) {
        const int row = tid * 2 + rr;            // 0..1023 = p*32 + h
        const int id  = idx_s[row];
        const int pm  = row >> 5;
        const float* pp = points + ((size_t)(batch * NPTS) + id) * 3;
        rel4[row + (row >> 3)] = make_float4(pp[0] - opt_s[pm * 3 + 0],
                                             pp[1] - opt_s[pm * 3 + 1],
                                             pp[2] - opt_s[pm * 3 + 2], 0.f);
    }
    __syncthreads();   // B2: rel ready

    // ---- compute all w A-frags for this wave's 4 points (held in registers) ----
    short8 af[4];
    {
        const float kx = kp_s[cl * 3 + 0];
        const float ky = kp_s[cl * 3 + 1];
        const float kz = kp_s[cl * 3 + 2];
        #pragma unroll
        for (int rp = 0; rp < 4; rp++) {
            const int p = rp * 8 + g;
            float wv[8];
            #pragma unroll
            for (int j = 0; j < 8; j++) {
                // row = p*32 + q*8 + j  ->  skewed index 36p + 9q + j
                const float4 rr = rel4[36 * p + 9 * q + j];    // broadcast across cl
                const float dx = rr.x - kx, dy = rr.y - ky, dz = rr.z - kz;
                const float d2 = dx * dx + dy * dy + dz * dz;
                wv[j] = fmaxf(1.f - __builtin_amdgcn_sqrtf(d2), 0.f);  // EXTENT=1
            }
            uint4 ua;
            ua.x = pack_trunc(wv[0], wv[1]);
            ua.y = pack_trunc(wv[2], wv[3]);
            ua.z = pack_trunc(wv[4], wv[5]);
            ua.w = pack_trunc(wv[6], wv[7]);
            af[rp] = __builtin_bit_cast(short8, ua);
        }
    }
    __syncthreads();   // B3: rel4 dead -> awf free for einsum1 output

    floatx4 a00 = {0.f, 0.f, 0.f, 0.f};   // row-tile 0, even kk
    floatx4 a01 = {0.f, 0.f, 0.f, 0.f};   // row-tile 0, odd kk
    floatx4 a10 = {0.f, 0.f, 0.f, 0.f};   // row-tile 1, even kk
    floatx4 a11 = {0.f, 0.f, 0.f, 0.f};   // row-tile 1, odd kk
    const int ct  = g & 3;                // col-tile of 16 C
    const int kh8 = (g >> 2) * 8;         // this wave's kk-range base within each half
    const unsigned short* vpg = vp + ct * 512 + lane * 8;
    unsigned short* dp = &feat_s[g * 1160 + sfc * 288 + sa * 2];   // sfc*8 rows of 36

    #pragma unroll
    for (int it = 0; it < 8; it++) {
        const int r  = it & 3;      // round (8 points each)
        const int p  = r * 8 + g;
        const int p4 = p & 15;
        const int pu = p >> 4;      // row-tile bit (wave-uniform)

        // (a) stage this iter's f-half from prefetched regs (wave-private LDS, no barrier)
        *(unsigned*)(dp + 0 * 36) = __builtin_amdgcn_perm(prbA.x, praA.x, 0x05040100u);
        *(unsigned*)(dp + 1 * 36) = __builtin_amdgcn_perm(prbA.x, praA.x, 0x07060302u);
        *(unsigned*)(dp + 2 * 36) = __builtin_amdgcn_perm(prbA.y, praA.y, 0x05040100u);
        *(unsigned*)(dp + 3 * 36) = __builtin_amdgcn_perm(prbA.y, praA.y, 0x07060302u);
        *(unsigned*)(dp + 4 * 36) = __builtin_amdgcn_perm(prbA.z, praA.z, 0x05040100u);
        *(unsigned*)(dp + 5 * 36) = __builtin_amdgcn_perm(prbA.z, praA.z, 0x07060302u);
        *(unsigned*)(dp + 6 * 36) = __builtin_amdgcn_perm(prbA.w, praA.w, 0x05040100u);
        *(unsigned*)(dp + 7 * 36) = __builtin_amdgcn_perm(prbA.w, praA.w, 0x07060302u);

        // (b) rotate pipeline and prefetch it+2 (fully unrolled -> rotation is free)
        praA = praB; prbA = prbB;
        if (it < 6) {
            const int nit = it + 2;
            const int nfh = nit >> 2, nr = nit & 3;
            const int srow = (nr * 8 + g) * 32 + sa * 2;
            const int id0 = idx_s[srow], id1 = idx_s[srow + 1];
            praB = *(const uint4*)(fbase + (size_t)id0 * NF + nfh * 32 + sfc * 8);
            prbB = *(const uint4*)(fbase + (size_t)id1 * NF + nfh * 32 + sfc * 8);
        }

        // (c) einsum1: 2 f-tiles of 16 for point p
        #pragma unroll
        for (int t = 0; t < 2; t++) {
            const uint4 ub = *(const uint4*)&feat_s[g * 1160 + (t * 16 + cl) * 36 + q * 8];
            floatx4 dd = {0.f, 0.f, 0.f, 0.f};
            dd = __builtin_amdgcn_mfma_f32_16x16x32_bf16(af[r], __builtin_bit_cast(short8, ub), dd, 0, 0, 0);
            const int kk    = 8 * t + (cl >> 1);               // local kappa-chunk 0..15
            const int q2    = (2 * cl + (q >> 1)) & 3;
            const int chunk = (p4 ^ kk) | (q2 << 4) | (pu << 6);
            unsigned* wp = (unsigned*)awf + kk * 512 + chunk * 4 + (q & 1) * 2;
            wp[0] = pack_trunc(dd[0], dd[1]);
            wp[1] = pack_trunc(dd[2], dd[3]);
        }

        // (d) at f-half boundary: einsum2 partial over this kappa-half
        if (it == 3) {
            __syncthreads();   // B4: awf (fh=0) complete
            __builtin_amdgcn_s_setprio(1);
            #pragma unroll 4
            for (int kkl = 0; kkl < 8; kkl++) {
                const int kka = kh8 + kkl;                       // kk within half, 0..15
                const uint4 uB = *(const uint4*)(vpg + (size_t)kka * 2048);
                const int ch = (cl ^ kka) | (q << 4);
                const uint4 uA0 = *(const uint4*)&awf[kka * 1024 + ch * 8];
                const uint4 uA1 = *(const uint4*)&awf[kka * 1024 + (ch | 64) * 8];
                if (kkl & 1) {
                    a01 = __builtin_amdgcn_mfma_f32_16x16x32_bf16(
                        __builtin_bit_cast(short8, uA0), __builtin_bit_cast(short8, uB), a01, 0, 0, 0);
                    a11 = __builtin_amdgcn_mfma_f32_16x16x32_bf16(
                        __builtin_bit_cast(short8, uA1), __builtin_bit_cast(short8, uB), a11, 0, 0, 0);
                } else {
                    a00 = __builtin_amdgcn_mfma_f32_16x16x32_bf16(
                        __builtin_bit_cast(short8, uA0), __builtin_bit_cast(short8, uB), a00, 0, 0, 0);
                    a10 = __builtin_amdgcn_mfma_f32_16x16x32_bf16(
                        __builtin_bit_cast(short8, uA1), __builtin_bit_cast(short8, uB), a10, 0, 0, 0);
                }
            }
            __builtin_amdgcn_s_setprio(0);
            __syncthreads();   // B5: einsum2 reads done -> awf reusable for fh=1
        }
    }

    // ---- einsum2 second kappa-half ----
    __syncthreads();   // B6: awf (fh=1) complete
    __builtin_amdgcn_s_setprio(1);
    #pragma unroll 4
    for (int kkl = 0; kkl < 8; kkl++) {
        const int kka = kh8 + kkl;
        const uint4 uB = *(const uint4*)(vpg + (size_t)(16 + kka) * 2048);
        const int ch = (cl ^ kka) | (q << 4);
        const uint4 uA0 = *(const uint4*)&awf[kka * 1024 + ch * 8];
        const uint4 uA1 = *(const uint4*)&awf[kka * 1024 + (ch | 64) * 8];
        if (kkl & 1) {
            a01 = __builtin_amdgcn_mfma_f32_16x16x32_bf16(
                __builtin_bit_cast(short8, uA0), __builtin_bit_cast(short8, uB), a01, 0, 0, 0);
            a11 = __builtin_amdgcn_mfma_f32_16x16x32_bf16(
                __builtin_bit_cast(short8, uA1), __builtin_bit_cast(short8, uB), a11, 0, 0, 0);
        } else {
            a00 = __builtin_amdgcn_mfma_f32_16x16x32_bf16(
                __builtin_bit_cast(short8, uA0), __builtin_bit_cast(short8, uB), a00, 0, 0, 0);
            a10 = __builtin_amdgcn_mfma_f32_16x16x32_bf16(
                __builtin_bit_cast(short8, uA1), __builtin_bit_cast(short8, uB), a10, 0, 0, 0);
        }
    }
    __builtin_amdgcn_s_setprio(0);

    // ---- epilogue: cross-wave (kh) reduction via ob[2][32][68], coalesced store ----
    __syncthreads();   // B7: all einsum2 reads of awf done
    float* ob = (float*)awf;                    // [kh][row 0..31][68] = 17408 B
    const int kh = g >> 2;
    #pragma unroll
    for (int ri = 0; ri < 4; ri++) {
        ob[(kh * 32 +      q * 4 + ri) * 68 + ct * 16 + cl] = a00[ri] + a01[ri];
        ob[(kh * 32 + 16 + q * 4 + ri) * 68 + ct * 16 + cl] = a10[ri] + a11[ri];
    }
    __syncthreads();   // B8: staged
    {
        const int row = tid >> 4;               // 0..31
        const int c4  = tid & 15;               // float4 slot
        const floatx4 v0 = *(const floatx4*)&ob[row * 68 + c4 * 4];
        const floatx4 v1 = *(const floatx4*)&ob[(32 + row) * 68 + c4 * 4];
        const floatx4 v = v0 + v1;
        floatx4* dst = (floatx4*)&out[((size_t)(batch * MPTS + m0 + row)) * NC + c4 * 4];
        __builtin_nontemporal_store(v, dst);    // out never re-read: bypass L2
    }
}

extern "C" void kernel_launch(void* const* d_in, const int* in_sizes, int n_in,
                              void* d_out, int out_size, void* d_ws, size_t ws_size,
                              hipStream_t stream) {
    const float* points   = (const float*)d_in[0];
    const float* features = (const float*)d_in[1];
    const float* outpts   = (const float*)d_in[2];
    const float* kpts     = (const float*)d_in[3];
    const float* kvals    = (const float*)d_in[4];
    const int*   nbr      = (const int*)d_in[5];
    float* out = (float*)d_out;

    unsigned short* vp     = (unsigned short*)d_ws;                   // 131072 B
    unsigned short* featbf = (unsigned short*)((char*)d_ws + 131072); // 8 MB

    prep_kernel<<<2080, 256, 0, stream>>>(kvals, features, vp, featbf);

    const int blocks = BATCH * (MPTS / 32);   // 2048
    kpconv_kernel<<<blocks, 512, 0, stream>>>(points, featbf, outpts, kpts, vp, nbr, out);
}